// Round 1
// baseline (443.466 us; speedup 1.0000x reference)
//
#include <hip/hip_runtime.h>

// Problem constants (from reference): B=32, H=24, N=500, F_IN=64, F_OUT=4, M=16
#define Bc   32
#define Oc   12000      // H*N
#define FINc 64
#define Mc   16

// One thread handles one (b, o) unit:
//   mu[4]     = x[b,o,:] @ mu_w[o]    + mu_b[o]
//   sigma[16] = x[b,o,:] @ sigma_w[o] + sigma_b[o]   (k = l*4 + j)
//   for m: out[m,b,o,l] = mu[l] + sum_j sigma[l*4+j] * eps[m,b,o,j]
// Block = 256 threads = 8 consecutive o (fast, for eps/out coalescing) x 32 b
// (so each o's weights are consumed entirely within one block -> HBM once).
__global__ __launch_bounds__(256) void mgr_fused_kernel(
    const float* __restrict__ x,        // [B, O, 64]
    const float* __restrict__ mu_w,     // [O, 64, 4]
    const float* __restrict__ mu_b,     // [O, 4]
    const float* __restrict__ sigma_w,  // [O, 64, 16]
    const float* __restrict__ sigma_b,  // [O, 16]
    const float* __restrict__ eps,      // [M, B, O, 4]
    float* __restrict__ out)            // [M, B, O, 4]
{
    const int tid = threadIdx.x;
    const int oi  = tid & 7;
    const int bi  = tid >> 3;           // 0..31
    const int o   = blockIdx.x * 8 + oi;

    const float4* __restrict__ x4   = reinterpret_cast<const float4*>(x) + (bi * Oc + o) * 16;
    const float4* __restrict__ muw4 = reinterpret_cast<const float4*>(mu_w) + o * 64;
    const float4* __restrict__ sw4  = reinterpret_cast<const float4*>(sigma_w) + o * 256;

    // accumulators, initialized with biases
    float4 amu = reinterpret_cast<const float4*>(mu_b)[o];
    float4 as0 = reinterpret_cast<const float4*>(sigma_b)[o * 4 + 0]; // l=0, j=0..3
    float4 as1 = reinterpret_cast<const float4*>(sigma_b)[o * 4 + 1]; // l=1
    float4 as2 = reinterpret_cast<const float4*>(sigma_b)[o * 4 + 2]; // l=2
    float4 as3 = reinterpret_cast<const float4*>(sigma_b)[o * 4 + 3]; // l=3

    auto step = [&](float xs, int f) {
        float4 w = muw4[f];
        amu.x = fmaf(xs, w.x, amu.x);
        amu.y = fmaf(xs, w.y, amu.y);
        amu.z = fmaf(xs, w.z, amu.z);
        amu.w = fmaf(xs, w.w, amu.w);
        float4 s;
        s = sw4[4 * f + 0];
        as0.x = fmaf(xs, s.x, as0.x); as0.y = fmaf(xs, s.y, as0.y);
        as0.z = fmaf(xs, s.z, as0.z); as0.w = fmaf(xs, s.w, as0.w);
        s = sw4[4 * f + 1];
        as1.x = fmaf(xs, s.x, as1.x); as1.y = fmaf(xs, s.y, as1.y);
        as1.z = fmaf(xs, s.z, as1.z); as1.w = fmaf(xs, s.w, as1.w);
        s = sw4[4 * f + 2];
        as2.x = fmaf(xs, s.x, as2.x); as2.y = fmaf(xs, s.y, as2.y);
        as2.z = fmaf(xs, s.z, as2.z); as2.w = fmaf(xs, s.w, as2.w);
        s = sw4[4 * f + 3];
        as3.x = fmaf(xs, s.x, as3.x); as3.y = fmaf(xs, s.y, as3.y);
        as3.z = fmaf(xs, s.z, as3.z); as3.w = fmaf(xs, s.w, as3.w);
    };

    #pragma unroll 4
    for (int fo = 0; fo < 16; ++fo) {
        float4 xv = x4[fo];
        step(xv.x, 4 * fo + 0);
        step(xv.y, 4 * fo + 1);
        step(xv.z, 4 * fo + 2);
        step(xv.w, 4 * fo + 3);
    }

    const float4* __restrict__ eps4 = reinterpret_cast<const float4*>(eps);
    float4* __restrict__ out4 = reinterpret_cast<float4*>(out);

    #pragma unroll 4
    for (int m = 0; m < Mc; ++m) {
        const int idx = (m * Bc + bi) * Oc + o;
        float4 e = eps4[idx];
        float4 r;
        r.x = amu.x + as0.x * e.x + as0.y * e.y + as0.z * e.z + as0.w * e.w;
        r.y = amu.y + as1.x * e.x + as1.y * e.y + as1.z * e.z + as1.w * e.w;
        r.z = amu.z + as2.x * e.x + as2.y * e.y + as2.z * e.z + as2.w * e.w;
        r.w = amu.w + as3.x * e.x + as3.y * e.y + as3.z * e.z + as3.w * e.w;
        out4[idx] = r;
    }
}

extern "C" void kernel_launch(void* const* d_in, const int* in_sizes, int n_in,
                              void* d_out, int out_size, void* d_ws, size_t ws_size,
                              hipStream_t stream) {
    const float* x       = (const float*)d_in[0];
    const float* mu_w    = (const float*)d_in[1];
    const float* mu_b    = (const float*)d_in[2];
    const float* sigma_w = (const float*)d_in[3];
    const float* sigma_b = (const float*)d_in[4];
    const float* eps     = (const float*)d_in[5];
    float* out = (float*)d_out;

    dim3 grid(Oc / 8);   // 1500 blocks
    dim3 block(256);
    mgr_fused_kernel<<<grid, block, 0, stream>>>(x, mu_w, mu_b, sigma_w, sigma_b, eps, out);
}

// Round 2
// 291.576 us; speedup vs baseline: 1.5209x; 1.5209x over previous
//
#include <hip/hip_runtime.h>

// Problem constants: B=32, H=24, N=500, F_IN=64, F_OUT=4, M=16, O=H*N=12000
#define Bc   32
#define Oc   12000
#define Mc   16

// Block = 256 threads = 8 consecutive o x 32 b. Weights for the block's 8 o's
// (40 KB) are staged in LDS once (coalesced), then the 32-way b-redundancy is
// served by LDS broadcast instead of L1/L2 (R1 showed latency-bound: VALUBusy
// 6.5%, HBM 13%, weight loads thrash 32KB L1).
//
// LDS padding: per-o stride 257 float4 (sigma_w) / 65 float4 (mu_w) so the 8
// distinct oi addresses of a wave-wide ds_read_b128 start at banks 4*(oi+c)
// mod 32 -> exactly tile the 32 banks, conflict-free.
__global__ __launch_bounds__(256) void mgr_fused_kernel(
    const float* __restrict__ x,        // [B, O, 64]
    const float* __restrict__ mu_w,     // [O, 64, 4]
    const float* __restrict__ mu_b,     // [O, 4]
    const float* __restrict__ sigma_w,  // [O, 64, 16]
    const float* __restrict__ sigma_b,  // [O, 16]
    const float* __restrict__ eps,      // [M, B, O, 4]
    float* __restrict__ out)            // [M, B, O, 4]
{
    __shared__ float4 s_sw4[8 * 257];   // sigma_w: [oi][f*4 + l], padded
    __shared__ float4 s_muw4[8 * 65];   // mu_w:    [oi][f],       padded
    __shared__ float4 s_mub4[8];        // mu_b:    [oi]
    __shared__ float4 s_sb4[8 * 4];     // sigma_b: [oi][l]

    const int tid = threadIdx.x;
    const int blk = blockIdx.x;

    // ---- stage weights (coalesced; each iteration of sw covers exactly one o) ----
    const float4* __restrict__ g_sw4 = reinterpret_cast<const float4*>(sigma_w) + blk * 2048;
    #pragma unroll
    for (int it = 0; it < 8; ++it)
        s_sw4[it * 257 + tid] = g_sw4[it * 256 + tid];

    const float4* __restrict__ g_muw4 = reinterpret_cast<const float4*>(mu_w) + blk * 512;
    #pragma unroll
    for (int it = 0; it < 2; ++it) {
        int g = it * 256 + tid;
        s_muw4[(g >> 6) * 65 + (g & 63)] = g_muw4[g];
    }

    if (tid < 32) {
        s_sb4[tid] = reinterpret_cast<const float4*>(sigma_b)[blk * 32 + tid];
    } else if (tid < 40) {
        s_mub4[tid - 32] = reinterpret_cast<const float4*>(mu_b)[blk * 8 + (tid - 32)];
    }

    const int oi = tid & 7;
    const int bi = tid >> 3;
    const int o  = blk * 8 + oi;

    // ---- hoist x loads above the barrier (independent of LDS) ----
    const float4* __restrict__ x4 = reinterpret_cast<const float4*>(x) + (bi * Oc + o) * 16;
    float4 xv[16];
    #pragma unroll
    for (int i = 0; i < 16; ++i) xv[i] = x4[i];

    __syncthreads();

    float4 amu = s_mub4[oi];
    float4 as0 = s_sb4[oi * 4 + 0];
    float4 as1 = s_sb4[oi * 4 + 1];
    float4 as2 = s_sb4[oi * 4 + 2];
    float4 as3 = s_sb4[oi * 4 + 3];

    const float4* __restrict__ muw = &s_muw4[oi * 65];
    const float4* __restrict__ sw  = &s_sw4[oi * 257];

    #pragma unroll
    for (int fo = 0; fo < 16; ++fo) {
        const float4 xq = xv[fo];
        #pragma unroll
        for (int fi = 0; fi < 4; ++fi) {
            const int f = 4 * fo + fi;
            const float xs = (fi == 0) ? xq.x : (fi == 1) ? xq.y : (fi == 2) ? xq.z : xq.w;
            float4 w = muw[f];
            amu.x = fmaf(xs, w.x, amu.x);
            amu.y = fmaf(xs, w.y, amu.y);
            amu.z = fmaf(xs, w.z, amu.z);
            amu.w = fmaf(xs, w.w, amu.w);
            float4 s;
            s = sw[4 * f + 0];
            as0.x = fmaf(xs, s.x, as0.x); as0.y = fmaf(xs, s.y, as0.y);
            as0.z = fmaf(xs, s.z, as0.z); as0.w = fmaf(xs, s.w, as0.w);
            s = sw[4 * f + 1];
            as1.x = fmaf(xs, s.x, as1.x); as1.y = fmaf(xs, s.y, as1.y);
            as1.z = fmaf(xs, s.z, as1.z); as1.w = fmaf(xs, s.w, as1.w);
            s = sw[4 * f + 2];
            as2.x = fmaf(xs, s.x, as2.x); as2.y = fmaf(xs, s.y, as2.y);
            as2.z = fmaf(xs, s.z, as2.z); as2.w = fmaf(xs, s.w, as2.w);
            s = sw[4 * f + 3];
            as3.x = fmaf(xs, s.x, as3.x); as3.y = fmaf(xs, s.y, as3.y);
            as3.z = fmaf(xs, s.z, as3.z); as3.w = fmaf(xs, s.w, as3.w);
        }
    }

    // ---- epilogue: stream eps, write out (coalesced: o fast dim) ----
    const float4* __restrict__ eps4 = reinterpret_cast<const float4*>(eps);
    float4* __restrict__ out4 = reinterpret_cast<float4*>(out);

    #pragma unroll 4
    for (int m = 0; m < Mc; ++m) {
        const int idx = (m * Bc + bi) * Oc + o;
        float4 e = eps4[idx];
        float4 r;
        r.x = amu.x + as0.x * e.x + as0.y * e.y + as0.z * e.z + as0.w * e.w;
        r.y = amu.y + as1.x * e.x + as1.y * e.y + as1.z * e.z + as1.w * e.w;
        r.z = amu.z + as2.x * e.x + as2.y * e.y + as2.z * e.z + as2.w * e.w;
        r.w = amu.w + as3.x * e.x + as3.y * e.y + as3.z * e.z + as3.w * e.w;
        out4[idx] = r;
    }
}

extern "C" void kernel_launch(void* const* d_in, const int* in_sizes, int n_in,
                              void* d_out, int out_size, void* d_ws, size_t ws_size,
                              hipStream_t stream) {
    const float* x       = (const float*)d_in[0];
    const float* mu_w    = (const float*)d_in[1];
    const float* mu_b    = (const float*)d_in[2];
    const float* sigma_w = (const float*)d_in[3];
    const float* sigma_b = (const float*)d_in[4];
    const float* eps     = (const float*)d_in[5];
    float* out = (float*)d_out;

    dim3 grid(Oc / 8);   // 1500 blocks
    dim3 block(256);
    mgr_fused_kernel<<<grid, block, 0, stream>>>(x, mu_w, mu_b, sigma_w, sigma_b, eps, out);
}